// Round 1
// baseline (851.970 us; speedup 1.0000x reference)
//
#include <hip/hip_runtime.h>

#define BB 4
#define NN 2048
#define EE 8192
#define RH 150
#define OH 100

// ---------------------------------------------------------------------------
// Kernel 1: recover indices from dense one-hot [B, N, E] (value 1.0 at
// [b, idx[b,e], e]). Single coalesced pass, float4 loads.
// ---------------------------------------------------------------------------
__global__ void extract_idx_kernel(const float* __restrict__ M, int* __restrict__ idx) {
    const unsigned total4 = (unsigned)BB * NN * EE / 4u;  // 16,777,216
    unsigned i = blockIdx.x * blockDim.x + threadIdx.x;
    const unsigned stride = gridDim.x * blockDim.x;
    for (; i < total4; i += stride) {
        const float4 v = reinterpret_cast<const float4*>(M)[i];
        if (v.x > 0.5f || v.y > 0.5f || v.z > 0.5f || v.w > 0.5f) {
            const unsigned flat = i * 4u;
            const unsigned e = flat & (EE - 1u);
            const unsigned n = (flat >> 13) & (NN - 1u);
            const unsigned b = flat >> 24;  // / (E*N) = / 2^24
            if (v.x > 0.5f) idx[b * EE + e + 0u] = (int)n;
            if (v.y > 0.5f) idx[b * EE + e + 1u] = (int)n;
            if (v.z > 0.5f) idx[b * EE + e + 2u] = (int)n;
            if (v.w > 0.5f) idx[b * EE + e + 3u] = (int)n;
        }
    }
}

// ---------------------------------------------------------------------------
// Kernel 2: per-edge relational MLP (7 -> 150 relu -> 150 relu -> 1 sigmoid).
// One thread per edge; h1[150] kept in VGPRs via full unroll; weight reads are
// wave-uniform (loop counters uniform) -> scalar loads. 6 accumulators for ILP.
// PASS==0: atomicAdd sigmoid output into eff_rcv[b*N + rcv].
// PASS==1: write sigmoid output to out[b*E + e].
// ---------------------------------------------------------------------------
template <int PASS>
__global__ __launch_bounds__(64) void edge_mlp_kernel(
    const float* __restrict__ obj,
    const int* __restrict__ snd_idx, const int* __restrict__ rcv_idx,
    const float* __restrict__ rel,
    const float* __restrict__ W1, const float* __restrict__ b1,
    const float* __restrict__ W2, const float* __restrict__ b2,
    const float* __restrict__ W3, const float* __restrict__ b3,
    float* __restrict__ out)
{
    const int t = blockIdx.x * 64 + (int)threadIdx.x;  // grid sized exactly B*E
    const int b = t >> 13;                             // / E
    const int sn = snd_idx[t];
    const int rn = rcv_idx[t];

    float x[7];
    {
        const float* ps = obj + ((b << 11) + sn) * 3;
        x[0] = ps[0]; x[1] = ps[1]; x[2] = ps[2];
        const float* pr = obj + ((b << 11) + rn) * 3;
        x[3] = pr[0]; x[4] = pr[1]; x[5] = pr[2];
        x[6] = rel[t];
    }

    float h1[RH];
#pragma unroll
    for (int j = 0; j < RH; ++j) {
        float a = b1[j];
#pragma unroll
        for (int k = 0; k < 7; ++k) a = fmaf(x[k], W1[k * RH + j], a);
        h1[j] = fmaxf(a, 0.0f);
    }

    float o = b3[0];
    for (int jb = 0; jb < RH; jb += 6) {  // 150 = 25 * 6
        float a0 = b2[jb + 0], a1 = b2[jb + 1], a2 = b2[jb + 2];
        float a3 = b2[jb + 3], a4 = b2[jb + 4], a5 = b2[jb + 5];
#pragma unroll
        for (int k = 0; k < RH; ++k) {
            const float h = h1[k];
            const float* w = W2 + k * RH + jb;
            a0 = fmaf(h, w[0], a0);
            a1 = fmaf(h, w[1], a1);
            a2 = fmaf(h, w[2], a2);
            a3 = fmaf(h, w[3], a3);
            a4 = fmaf(h, w[4], a4);
            a5 = fmaf(h, w[5], a5);
        }
        o = fmaf(fmaxf(a0, 0.0f), W3[jb + 0], o);
        o = fmaf(fmaxf(a1, 0.0f), W3[jb + 1], o);
        o = fmaf(fmaxf(a2, 0.0f), W3[jb + 2], o);
        o = fmaf(fmaxf(a3, 0.0f), W3[jb + 3], o);
        o = fmaf(fmaxf(a4, 0.0f), W3[jb + 4], o);
        o = fmaf(fmaxf(a5, 0.0f), W3[jb + 5], o);
    }

    const float eff = 1.0f / (1.0f + __expf(-o));
    if (PASS == 0) {
        atomicAdd(&out[(b << 11) + rn], eff);
    } else {
        out[t] = eff;
    }
}

// ---------------------------------------------------------------------------
// Kernel 3: per-node object MLP (4 -> 100 relu -> 3).
// ---------------------------------------------------------------------------
__global__ void object_mlp_kernel(
    const float* __restrict__ obj, const float* __restrict__ eff_rcv,
    const float* __restrict__ W1, const float* __restrict__ b1,
    const float* __restrict__ W2, const float* __restrict__ b2,
    float* __restrict__ obj_new)
{
    const int t = blockIdx.x * blockDim.x + (int)threadIdx.x;
    if (t >= BB * NN) return;
    const float x0 = obj[t * 3 + 0];
    const float x1 = obj[t * 3 + 1];
    const float x2 = obj[t * 3 + 2];
    const float x3 = eff_rcv[t];
    float a0 = b2[0], a1 = b2[1], a2 = b2[2];
#pragma unroll
    for (int j = 0; j < OH; ++j) {
        float h = b1[j];
        h = fmaf(x0, W1[0 * OH + j], h);
        h = fmaf(x1, W1[1 * OH + j], h);
        h = fmaf(x2, W1[2 * OH + j], h);
        h = fmaf(x3, W1[3 * OH + j], h);
        h = fmaxf(h, 0.0f);
        a0 = fmaf(h, W2[j * 3 + 0], a0);
        a1 = fmaf(h, W2[j * 3 + 1], a1);
        a2 = fmaf(h, W2[j * 3 + 2], a2);
    }
    obj_new[t * 3 + 0] = a0;
    obj_new[t * 3 + 1] = a1;
    obj_new[t * 3 + 2] = a2;
}

// ---------------------------------------------------------------------------
extern "C" void kernel_launch(void* const* d_in, const int* in_sizes, int n_in,
                              void* d_out, int out_size, void* d_ws, size_t ws_size,
                              hipStream_t stream) {
    (void)in_sizes; (void)n_in; (void)out_size; (void)ws_size;

    const float* objects = (const float*)d_in[0];
    const float* S       = (const float*)d_in[1];
    const float* R       = (const float*)d_in[2];
    const float* rel     = (const float*)d_in[3];
    const float* rW1     = (const float*)d_in[4];
    const float* rb1     = (const float*)d_in[5];
    const float* rW2     = (const float*)d_in[6];
    const float* rb2     = (const float*)d_in[7];
    const float* rW3     = (const float*)d_in[8];
    const float* rb3     = (const float*)d_in[9];
    const float* oW1     = (const float*)d_in[10];
    const float* ob1     = (const float*)d_in[11];
    const float* oW2     = (const float*)d_in[12];
    const float* ob2     = (const float*)d_in[13];

    char* ws = (char*)d_ws;
    int*   snd_idx = (int*)(ws + 0);              // B*E ints   = 128 KiB
    int*   rcv_idx = (int*)(ws + (1 << 17));      // B*E ints   = 128 KiB
    float* eff_rcv = (float*)(ws + (1 << 18));    // B*N floats =  32 KiB
    float* obj_new = (float*)(ws + (1 << 18) + (BB * NN * 4));  // B*N*3 floats

    // 1) recover gather/scatter indices from the dense one-hot matrices
    extract_idx_kernel<<<2048, 256, 0, stream>>>(S, snd_idx);
    extract_idx_kernel<<<2048, 256, 0, stream>>>(R, rcv_idx);

    // 2) zero the scatter target
    hipMemsetAsync(eff_rcv, 0, BB * NN * sizeof(float), stream);

    // 3) recurrence iteration: edge MLP -> scatter-add to receivers
    edge_mlp_kernel<0><<<(BB * EE) / 64, 64, 0, stream>>>(
        objects, snd_idx, rcv_idx, rel, rW1, rb1, rW2, rb2, rW3, rb3, eff_rcv);

    // 4) object MLP -> new object states
    object_mlp_kernel<<<(BB * NN + 255) / 256, 256, 0, stream>>>(
        objects, eff_rcv, oW1, ob1, oW2, ob2, obj_new);

    // 5) final relational pass -> edge weights (the output)
    edge_mlp_kernel<1><<<(BB * EE) / 64, 64, 0, stream>>>(
        obj_new, snd_idx, rcv_idx, rel, rW1, rb1, rW2, rb2, rW3, rb3, (float*)d_out);
}

// Round 2
// 173.784 us; speedup vs baseline: 4.9025x; 4.9025x over previous
//
#include <hip/hip_runtime.h>

#define BB 4
#define NN 2048
#define EE 8192
#define RH 150
#define RHP 152      // RH padded to multiple of 4 (j and k pad, zero-filled)
#define LSTR 156     // LDS row stride in floats: multiple of 4, (156/4)=39 odd -> conflict-free b128
#define OH 100
#define JPW 38       // output neurons per wave: 4 waves * 38 = 152

// ---------------------------------------------------------------------------
// Kernel 1: recover indices from dense one-hot [B, N, E].
// ---------------------------------------------------------------------------
__global__ void extract_idx_kernel(const float* __restrict__ M, int* __restrict__ idx) {
    const unsigned total4 = (unsigned)BB * NN * EE / 4u;  // 16,777,216
    unsigned i = blockIdx.x * blockDim.x + threadIdx.x;
    const unsigned stride = gridDim.x * blockDim.x;
    for (; i < total4; i += stride) {
        const float4 v = reinterpret_cast<const float4*>(M)[i];
        if (v.x > 0.5f || v.y > 0.5f || v.z > 0.5f || v.w > 0.5f) {
            const unsigned flat = i * 4u;
            const unsigned e = flat & (EE - 1u);
            const unsigned n = (flat >> 13) & (NN - 1u);
            const unsigned b = flat >> 24;
            if (v.x > 0.5f) idx[b * EE + e + 0u] = (int)n;
            if (v.y > 0.5f) idx[b * EE + e + 1u] = (int)n;
            if (v.z > 0.5f) idx[b * EE + e + 2u] = (int)n;
            if (v.w > 0.5f) idx[b * EE + e + 3u] = (int)n;
        }
    }
}

// ---------------------------------------------------------------------------
// Kernel 1b: zero-pad relational weights into [RHP x RHP] / [RHP] buffers.
// ---------------------------------------------------------------------------
__global__ void pad_weights_kernel(const float* __restrict__ W2, const float* __restrict__ b2,
                                   const float* __restrict__ W3,
                                   float* __restrict__ W2p, float* __restrict__ b2p,
                                   float* __restrict__ W3p) {
    const int t = blockIdx.x * 256 + (int)threadIdx.x;
    if (t < RHP * RHP) {
        const int k = t / RHP, j = t - k * RHP;
        W2p[t] = (k < RH && j < RH) ? W2[k * RH + j] : 0.0f;
    }
    if (t < RHP) {
        b2p[t] = (t < RH) ? b2[t] : 0.0f;
        W3p[t] = (t < RH) ? W3[t] : 0.0f;
    }
}

// ---------------------------------------------------------------------------
// Kernel 2: block-cooperative edge MLP. 256 threads = 4 waves handle 64 edges.
//  phase 1: h1[64][RH] -> LDS (padded, zeros beyond RH)
//  phase 2: wave w computes output neurons j in [w*38, w*38+38); 38 VGPR
//           accumulators; inner loop: ds_read_b128 of h1 + wave-uniform
//           (s_load) W2p rows; then relu * W3 partial reduction.
//  phase 3: cross-wave LDS reduction, sigmoid, store/atomic.
// ---------------------------------------------------------------------------
template <int PASS>
__global__ __launch_bounds__(256) void edge_mlp_v2(
    const float* __restrict__ obj,
    const int* __restrict__ snd_idx, const int* __restrict__ rcv_idx,
    const float* __restrict__ rel,
    const float* __restrict__ W1, const float* __restrict__ b1,
    const float* __restrict__ W2p, const float* __restrict__ b2p,
    const float* __restrict__ W3p, const float* __restrict__ b3,
    float* __restrict__ out)
{
    __shared__ float h1s[64 * LSTR];
    __shared__ float xs[64][8];
    __shared__ float red[256];
    __shared__ int   rdst[64];

    const int t = (int)threadIdx.x;
    const int ebase = (int)blockIdx.x * 64;

    if (t < 64) {
        const int eg = ebase + t;
        const int b = eg >> 13;                 // / EE
        const int sn = snd_idx[eg];
        const int rn = rcv_idx[eg];
        const float* ps = obj + ((b << 11) + sn) * 3;
        const float* pr = obj + ((b << 11) + rn) * 3;
        xs[t][0] = ps[0]; xs[t][1] = ps[1]; xs[t][2] = ps[2];
        xs[t][3] = pr[0]; xs[t][4] = pr[1]; xs[t][5] = pr[2];
        xs[t][6] = rel[eg];
        rdst[t] = (b << 11) + rn;
    }
    __syncthreads();

    // phase 1: layer 1 into LDS
    for (int idx = t; idx < 64 * LSTR; idx += 256) {
        const int e = idx / LSTR;
        const int j = idx - e * LSTR;
        float v = 0.0f;
        if (j < RH) {
            v = b1[j];
#pragma unroll
            for (int k = 0; k < 7; ++k) v = fmaf(xs[e][k], W1[k * RH + j], v);
            v = fmaxf(v, 0.0f);
        }
        h1s[idx] = v;
    }
    __syncthreads();

    // phase 2: layers 2+3, wave-parallel over output neurons
    const int w = __builtin_amdgcn_readfirstlane(t >> 6);
    const int l = t & 63;
    const int jbase = w * JPW;

    float acc[JPW];
#pragma unroll
    for (int m = 0; m < JPW; ++m) acc[m] = b2p[jbase + m];

    const float* hrow = h1s + l * LSTR;
    for (int kc = 0; kc < RHP; kc += 4) {
        const float4 hv = *reinterpret_cast<const float4*>(hrow + kc);
        const float* r0 = W2p + (kc + 0) * RHP + jbase;
        const float* r1 = r0 + RHP;
        const float* r2 = r1 + RHP;
        const float* r3 = r2 + RHP;
#pragma unroll
        for (int m = 0; m < JPW; ++m) {
            float a = acc[m];
            a = fmaf(hv.x, r0[m], a);
            a = fmaf(hv.y, r1[m], a);
            a = fmaf(hv.z, r2[m], a);
            a = fmaf(hv.w, r3[m], a);
            acc[m] = a;
        }
    }

    float o = 0.0f;
#pragma unroll
    for (int m = 0; m < JPW; ++m)
        o = fmaf(fmaxf(acc[m], 0.0f), W3p[jbase + m], o);

    red[t] = o;
    __syncthreads();

    if (t < 64) {
        const float tot = red[t] + red[64 + t] + red[128 + t] + red[192 + t] + b3[0];
        const float eff = 1.0f / (1.0f + __expf(-tot));
        if (PASS == 0) atomicAdd(&out[rdst[t]], eff);
        else           out[ebase + t] = eff;
    }
}

// ---------------------------------------------------------------------------
// Kernel 3: per-node object MLP (4 -> 100 relu -> 3).
// ---------------------------------------------------------------------------
__global__ void object_mlp_kernel(
    const float* __restrict__ obj, const float* __restrict__ eff_rcv,
    const float* __restrict__ W1, const float* __restrict__ b1,
    const float* __restrict__ W2, const float* __restrict__ b2,
    float* __restrict__ obj_new)
{
    const int t = blockIdx.x * blockDim.x + (int)threadIdx.x;
    if (t >= BB * NN) return;
    const float x0 = obj[t * 3 + 0];
    const float x1 = obj[t * 3 + 1];
    const float x2 = obj[t * 3 + 2];
    const float x3 = eff_rcv[t];
    float a0 = b2[0], a1 = b2[1], a2 = b2[2];
#pragma unroll
    for (int j = 0; j < OH; ++j) {
        float h = b1[j];
        h = fmaf(x0, W1[0 * OH + j], h);
        h = fmaf(x1, W1[1 * OH + j], h);
        h = fmaf(x2, W1[2 * OH + j], h);
        h = fmaf(x3, W1[3 * OH + j], h);
        h = fmaxf(h, 0.0f);
        a0 = fmaf(h, W2[j * 3 + 0], a0);
        a1 = fmaf(h, W2[j * 3 + 1], a1);
        a2 = fmaf(h, W2[j * 3 + 2], a2);
    }
    obj_new[t * 3 + 0] = a0;
    obj_new[t * 3 + 1] = a1;
    obj_new[t * 3 + 2] = a2;
}

// ---------------------------------------------------------------------------
extern "C" void kernel_launch(void* const* d_in, const int* in_sizes, int n_in,
                              void* d_out, int out_size, void* d_ws, size_t ws_size,
                              hipStream_t stream) {
    (void)in_sizes; (void)n_in; (void)out_size; (void)ws_size;

    const float* objects = (const float*)d_in[0];
    const float* S       = (const float*)d_in[1];
    const float* R       = (const float*)d_in[2];
    const float* rel     = (const float*)d_in[3];
    const float* rW1     = (const float*)d_in[4];
    const float* rb1     = (const float*)d_in[5];
    const float* rW2     = (const float*)d_in[6];
    const float* rb2     = (const float*)d_in[7];
    const float* rW3     = (const float*)d_in[8];
    const float* rb3     = (const float*)d_in[9];
    const float* oW1     = (const float*)d_in[10];
    const float* ob1     = (const float*)d_in[11];
    const float* oW2     = (const float*)d_in[12];
    const float* ob2     = (const float*)d_in[13];

    char* ws = (char*)d_ws;
    int*   snd_idx = (int*)(ws + 0);               // 128 KiB
    int*   rcv_idx = (int*)(ws + (128 << 10));     // 128 KiB
    float* eff_rcv = (float*)(ws + (256 << 10));   //  32 KiB
    float* obj_new = (float*)(ws + (288 << 10));   //  96 KiB
    float* W2p     = (float*)(ws + (384 << 10));   //  92.4 KiB (152*152*4)
    float* b2p     = (float*)(ws + (480 << 10));   //  608 B
    float* W3p     = (float*)(ws + (481 << 10));   //  608 B

    // 1) recover indices from one-hot matrices (mandatory 537 MB HBM read)
    extract_idx_kernel<<<2048, 256, 0, stream>>>(S, snd_idx);
    extract_idx_kernel<<<2048, 256, 0, stream>>>(R, rcv_idx);

    // 1b) pad relational weights
    pad_weights_kernel<<<(RHP * RHP + 255) / 256, 256, 0, stream>>>(
        rW2, rb2, rW3, W2p, b2p, W3p);

    // 2) zero the scatter target
    hipMemsetAsync(eff_rcv, 0, BB * NN * sizeof(float), stream);

    // 3) edge MLP pass 0 -> scatter-add effects to receivers
    edge_mlp_v2<0><<<(BB * EE) / 64, 256, 0, stream>>>(
        objects, snd_idx, rcv_idx, rel, rW1, rb1, W2p, b2p, W3p, rb3, eff_rcv);

    // 4) object MLP -> new object states
    object_mlp_kernel<<<(BB * NN + 255) / 256, 256, 0, stream>>>(
        objects, eff_rcv, oW1, ob1, oW2, ob2, obj_new);

    // 5) final relational pass -> edge weights (the output)
    edge_mlp_v2<1><<<(BB * EE) / 64, 256, 0, stream>>>(
        obj_new, snd_idx, rcv_idx, rel, rW1, rb1, W2p, b2p, W3p, rb3, (float*)d_out);
}

// Round 3
// 140.668 us; speedup vs baseline: 6.0566x; 1.2354x over previous
//
#include <hip/hip_runtime.h>

#define BB 4
#define NN 2048
#define EE 8192
#define RH 150
#define RHP 152      // RH padded (zero-filled) so 8 waves * 19 = 152 covers it
#define LSTR 156     // LDS row stride (floats): 156%32=28 -> 2-way bank alias on b128 (free)
#define OH 100
#define JPW 19       // output neurons per wave: 8 waves * 19 = 152

typedef float f4_t __attribute__((ext_vector_type(4)));

// ---------------------------------------------------------------------------
// Kernel 1: recover indices from BOTH dense one-hot [B, N, E] matrices.
// blocks [0,2048) scan S -> snd_idx, blocks [2048,4096) scan R -> rcv_idx.
// Non-temporal float4 loads (537 MB streamed once, > L3).
// ---------------------------------------------------------------------------
__global__ __launch_bounds__(256) void extract_idx2_kernel(
    const float* __restrict__ S, const float* __restrict__ R,
    int* __restrict__ snd_idx, int* __restrict__ rcv_idx)
{
    const bool second = blockIdx.x >= 2048;
    const float* __restrict__ M = second ? R : S;
    int* __restrict__ idx = second ? rcv_idx : snd_idx;

    const unsigned total4 = (unsigned)BB * NN * EE / 4u;  // 16,777,216
    unsigned i = (blockIdx.x & 2047u) * 256u + threadIdx.x;
    const unsigned stride = 2048u * 256u;
    for (; i < total4; i += stride) {
        const f4_t v = __builtin_nontemporal_load(reinterpret_cast<const f4_t*>(M) + i);
        if (v.x > 0.5f || v.y > 0.5f || v.z > 0.5f || v.w > 0.5f) {
            const unsigned flat = i * 4u;
            const unsigned e = flat & (EE - 1u);
            const unsigned n = (flat >> 13) & (NN - 1u);
            const unsigned b = flat >> 24;
            if (v.x > 0.5f) idx[b * EE + e + 0u] = (int)n;
            if (v.y > 0.5f) idx[b * EE + e + 1u] = (int)n;
            if (v.z > 0.5f) idx[b * EE + e + 2u] = (int)n;
            if (v.w > 0.5f) idx[b * EE + e + 3u] = (int)n;
        }
    }
}

// ---------------------------------------------------------------------------
// Kernel 1b: zero-pad relational weights into [RHP x RHP] / [RHP] buffers.
// ---------------------------------------------------------------------------
__global__ void pad_weights_kernel(const float* __restrict__ W2, const float* __restrict__ b2,
                                   const float* __restrict__ W3,
                                   float* __restrict__ W2p, float* __restrict__ b2p,
                                   float* __restrict__ W3p) {
    const int t = blockIdx.x * 256 + (int)threadIdx.x;
    if (t < RHP * RHP) {
        const int k = t / RHP, j = t - k * RHP;
        W2p[t] = (k < RH && j < RH) ? W2[k * RH + j] : 0.0f;
    }
    if (t < RHP) {
        b2p[t] = (t < RH) ? b2[t] : 0.0f;
        W3p[t] = (t < RH) ? W3[t] : 0.0f;
    }
}

// ---------------------------------------------------------------------------
// Kernel 2: block-cooperative edge MLP. 512 threads = 8 waves handle 64 edges
// (4 waves/SIMD at 2 blocks/CU -> latency hiding for s_load/ds_read).
//  phase 1: h1[64][RH] -> LDS; thread t owns edge (t&63), j strided by 8.
//  phase 2: wave w computes j in [w*19, w*19+19); 19 VGPR accumulators;
//           inner loop: ds_read_b128 of h + wave-uniform (s_load) W2p rows.
//  phase 3: cross-wave LDS reduction (8 partials), sigmoid, store/atomic.
// ---------------------------------------------------------------------------
template <int PASS>
__global__ __launch_bounds__(512) void edge_mlp_v3(
    const float* __restrict__ obj,
    const int* __restrict__ snd_idx, const int* __restrict__ rcv_idx,
    const float* __restrict__ rel,
    const float* __restrict__ W1, const float* __restrict__ b1,
    const float* __restrict__ W2p, const float* __restrict__ b2p,
    const float* __restrict__ W3p, const float* __restrict__ b3,
    float* __restrict__ out)
{
    __shared__ float h1s[64 * LSTR];
    __shared__ float red[512];

    const int t = (int)threadIdx.x;
    const int ebase = (int)blockIdx.x * 64;
    const int e = t & 63;
    const int jg = t >> 6;               // 0..7, wave-uniform
    const int eg = ebase + e;
    const int b = eg >> 13;

    // per-thread gathered inputs (8x redundant across waves; L1 broadcast)
    float x[7];
    {
        const int sn = snd_idx[eg];
        const int rn = rcv_idx[eg];
        const float* ps = obj + ((b << 11) + sn) * 3;
        const float* pr = obj + ((b << 11) + rn) * 3;
        x[0] = ps[0]; x[1] = ps[1]; x[2] = ps[2];
        x[3] = pr[0]; x[4] = pr[1]; x[5] = pr[2];
        x[6] = rel[eg];
    }

    // phase 1: layer 1 into LDS (j wave-uniform -> W1/b1 via s_load)
    for (int j = jg; j < LSTR; j += 8) {
        float v = 0.0f;
        if (j < RH) {
            v = b1[j];
#pragma unroll
            for (int k = 0; k < 7; ++k) v = fmaf(x[k], W1[k * RH + j], v);
            v = fmaxf(v, 0.0f);
        }
        h1s[e * LSTR + j] = v;
    }
    __syncthreads();

    // phase 2: layers 2+3, wave-parallel over output neurons
    const int w = __builtin_amdgcn_readfirstlane(jg);
    const int jbase = w * JPW;

    float acc[JPW];
#pragma unroll
    for (int m = 0; m < JPW; ++m) acc[m] = b2p[jbase + m];

    const float* hrow = h1s + e * LSTR;
    for (int kc = 0; kc < RHP; kc += 4) {
        const float4 hv = *reinterpret_cast<const float4*>(hrow + kc);
        const float* r0 = W2p + (kc + 0) * RHP + jbase;
        const float* r1 = r0 + RHP;
        const float* r2 = r1 + RHP;
        const float* r3 = r2 + RHP;
#pragma unroll
        for (int m = 0; m < JPW; ++m) {
            float a = acc[m];
            a = fmaf(hv.x, r0[m], a);
            a = fmaf(hv.y, r1[m], a);
            a = fmaf(hv.z, r2[m], a);
            a = fmaf(hv.w, r3[m], a);
            acc[m] = a;
        }
    }

    float o = 0.0f;
#pragma unroll
    for (int m = 0; m < JPW; ++m)
        o = fmaf(fmaxf(acc[m], 0.0f), W3p[jbase + m], o);

    red[t] = o;
    __syncthreads();

    // phase 3: reduce 8 wave-partials per edge
    if (t < 64) {
        float tot = b3[0];
#pragma unroll
        for (int i = 0; i < 8; ++i) tot += red[t + 64 * i];
        const float eff = 1.0f / (1.0f + __expf(-tot));
        if (PASS == 0) atomicAdd(&out[(b << 11) + rcv_idx[eg]], eff);
        else           out[eg] = eff;
    }
}

// ---------------------------------------------------------------------------
// Kernel 3: per-node object MLP (4 -> 100 relu -> 3).
// ---------------------------------------------------------------------------
__global__ void object_mlp_kernel(
    const float* __restrict__ obj, const float* __restrict__ eff_rcv,
    const float* __restrict__ W1, const float* __restrict__ b1,
    const float* __restrict__ W2, const float* __restrict__ b2,
    float* __restrict__ obj_new)
{
    const int t = blockIdx.x * blockDim.x + (int)threadIdx.x;
    if (t >= BB * NN) return;
    const float x0 = obj[t * 3 + 0];
    const float x1 = obj[t * 3 + 1];
    const float x2 = obj[t * 3 + 2];
    const float x3 = eff_rcv[t];
    float a0 = b2[0], a1 = b2[1], a2 = b2[2];
#pragma unroll
    for (int j = 0; j < OH; ++j) {
        float h = b1[j];
        h = fmaf(x0, W1[0 * OH + j], h);
        h = fmaf(x1, W1[1 * OH + j], h);
        h = fmaf(x2, W1[2 * OH + j], h);
        h = fmaf(x3, W1[3 * OH + j], h);
        h = fmaxf(h, 0.0f);
        a0 = fmaf(h, W2[j * 3 + 0], a0);
        a1 = fmaf(h, W2[j * 3 + 1], a1);
        a2 = fmaf(h, W2[j * 3 + 2], a2);
    }
    obj_new[t * 3 + 0] = a0;
    obj_new[t * 3 + 1] = a1;
    obj_new[t * 3 + 2] = a2;
}

// ---------------------------------------------------------------------------
extern "C" void kernel_launch(void* const* d_in, const int* in_sizes, int n_in,
                              void* d_out, int out_size, void* d_ws, size_t ws_size,
                              hipStream_t stream) {
    (void)in_sizes; (void)n_in; (void)out_size; (void)ws_size;

    const float* objects = (const float*)d_in[0];
    const float* S       = (const float*)d_in[1];
    const float* R       = (const float*)d_in[2];
    const float* rel     = (const float*)d_in[3];
    const float* rW1     = (const float*)d_in[4];
    const float* rb1     = (const float*)d_in[5];
    const float* rW2     = (const float*)d_in[6];
    const float* rb2     = (const float*)d_in[7];
    const float* rW3     = (const float*)d_in[8];
    const float* rb3     = (const float*)d_in[9];
    const float* oW1     = (const float*)d_in[10];
    const float* ob1     = (const float*)d_in[11];
    const float* oW2     = (const float*)d_in[12];
    const float* ob2     = (const float*)d_in[13];

    char* ws = (char*)d_ws;
    int*   snd_idx = (int*)(ws + 0);               // 128 KiB
    int*   rcv_idx = (int*)(ws + (128 << 10));     // 128 KiB
    float* eff_rcv = (float*)(ws + (256 << 10));   //  32 KiB
    float* obj_new = (float*)(ws + (288 << 10));   //  96 KiB
    float* W2p     = (float*)(ws + (384 << 10));   //  ~92 KiB (152*152*4)
    float* b2p     = (float*)(ws + (480 << 10));   //  608 B
    float* W3p     = (float*)(ws + (481 << 10));   //  608 B

    // 1) recover indices from both one-hot matrices (mandatory 537 MB read)
    extract_idx2_kernel<<<4096, 256, 0, stream>>>(S, R, snd_idx, rcv_idx);

    // 1b) pad relational weights; 2) zero the scatter target
    pad_weights_kernel<<<(RHP * RHP + 255) / 256, 256, 0, stream>>>(
        rW2, rb2, rW3, W2p, b2p, W3p);
    hipMemsetAsync(eff_rcv, 0, BB * NN * sizeof(float), stream);

    // 3) edge MLP pass 0 -> scatter-add effects to receivers
    edge_mlp_v3<0><<<(BB * EE) / 64, 512, 0, stream>>>(
        objects, snd_idx, rcv_idx, rel, rW1, rb1, W2p, b2p, W3p, rb3, eff_rcv);

    // 4) object MLP -> new object states
    object_mlp_kernel<<<(BB * NN + 255) / 256, 256, 0, stream>>>(
        objects, eff_rcv, oW1, ob1, oW2, ob2, obj_new);

    // 5) final relational pass -> edge weights (the output)
    edge_mlp_v3<1><<<(BB * EE) / 64, 512, 0, stream>>>(
        obj_new, snd_idx, rcv_idx, rel, rW1, rb1, W2p, b2p, W3p, rb3, (float*)d_out);
}

// Round 5
// 136.102 us; speedup vs baseline: 6.2598x; 1.0335x over previous
//
#include <hip/hip_runtime.h>

#define BB 4
#define NN 2048
#define EE 8192
#define RH 150
#define RHP 152      // RH padded (zero-filled); 8 waves * 19 = 152
#define LSTR 156     // LDS row stride (floats); 2-way bank alias on b128 (free)
#define OH 100
#define JPW 19       // output neurons per wave

typedef float f4_t __attribute__((ext_vector_type(4)));

// ---------------------------------------------------------------------------
// Kernel 1: scan both one-hot matrices -> indices; also zero-pads relational
// weights into ws and zeros eff_rcv (small-gtid threads). One dispatch.
// blocks [0,2048) scan S, [2048,4096) scan R. Non-temporal float4 streaming.
// ---------------------------------------------------------------------------
__global__ __launch_bounds__(256) void scan_prep_kernel(
    const float* __restrict__ S, const float* __restrict__ R,
    const float* __restrict__ rW2, const float* __restrict__ rb2,
    const float* __restrict__ rW3,
    int* __restrict__ snd_idx, int* __restrict__ rcv_idx,
    float* __restrict__ W2p, float* __restrict__ b2p, float* __restrict__ W3p,
    float* __restrict__ eff_rcv)
{
    const unsigned gtid = blockIdx.x * 256u + threadIdx.x;

    // ---- prep: pad weights + zero scatter target ----
    if (gtid < RHP * RHP) {
        const int k = (int)gtid / RHP, j = (int)gtid - k * RHP;
        W2p[gtid] = (k < RH && j < RH) ? rW2[k * RH + j] : 0.0f;
    }
    if (gtid < RHP) {
        b2p[gtid] = (gtid < RH) ? rb2[gtid] : 0.0f;
        W3p[gtid] = (gtid < RH) ? rW3[gtid] : 0.0f;
    }
    if (gtid < BB * NN) eff_rcv[gtid] = 0.0f;

    // ---- scan ----
    const bool second = blockIdx.x >= 2048;
    const float* __restrict__ M = second ? R : S;
    int* __restrict__ idx = second ? rcv_idx : snd_idx;

    const unsigned total4 = (unsigned)BB * NN * EE / 4u;  // 16,777,216
    unsigned i = (blockIdx.x & 2047u) * 256u + threadIdx.x;
    const unsigned stride = 2048u * 256u;
    for (; i < total4; i += stride) {
        const f4_t v = __builtin_nontemporal_load(reinterpret_cast<const f4_t*>(M) + i);
        if (v.x > 0.5f || v.y > 0.5f || v.z > 0.5f || v.w > 0.5f) {
            const unsigned flat = i * 4u;
            const unsigned e = flat & (EE - 1u);
            const unsigned n = (flat >> 13) & (NN - 1u);
            const unsigned b = flat >> 24;
            if (v.x > 0.5f) idx[b * EE + e + 0u] = (int)n;
            if (v.y > 0.5f) idx[b * EE + e + 1u] = (int)n;
            if (v.z > 0.5f) idx[b * EE + e + 2u] = (int)n;
            if (v.w > 0.5f) idx[b * EE + e + 3u] = (int)n;
        }
    }
}

// ---------------------------------------------------------------------------
// Shared edge-MLP body: layers 1-3 for 64 edges per block, 8 waves.
// x[7] already gathered by caller. Writes per-edge sigmoid into red-reduced
// value; returns it to caller for the (t<64) storing lanes.
// ---------------------------------------------------------------------------
__device__ __forceinline__ float edge_mlp_body(
    const float x[7], int t, int e, int jg,
    const float* __restrict__ W1, const float* __restrict__ b1,
    const float* __restrict__ W2p, const float* __restrict__ b2p,
    const float* __restrict__ W3p, const float* __restrict__ b3,
    float* __restrict__ h1s, float* __restrict__ red)
{
    // layer 1 into LDS (j wave-uniform -> W1/b1 via s_load)
    for (int j = jg; j < LSTR; j += 8) {
        float v = 0.0f;
        if (j < RH) {
            v = b1[j];
#pragma unroll
            for (int k = 0; k < 7; ++k) v = fmaf(x[k], W1[k * RH + j], v);
            v = fmaxf(v, 0.0f);
        }
        h1s[e * LSTR + j] = v;
    }
    __syncthreads();

    // layers 2+3, wave-parallel over output neurons
    const int w = __builtin_amdgcn_readfirstlane(jg);
    const int jbase = w * JPW;

    float acc[JPW];
#pragma unroll
    for (int m = 0; m < JPW; ++m) acc[m] = b2p[jbase + m];

    const float* hrow = h1s + e * LSTR;
    for (int kc = 0; kc < RHP; kc += 4) {
        const float4 hv = *reinterpret_cast<const float4*>(hrow + kc);
        const float* r0 = W2p + (kc + 0) * RHP + jbase;
        const float* r1 = r0 + RHP;
        const float* r2 = r1 + RHP;
        const float* r3 = r2 + RHP;
#pragma unroll
        for (int m = 0; m < JPW; ++m) {
            float a = acc[m];
            a = fmaf(hv.x, r0[m], a);
            a = fmaf(hv.y, r1[m], a);
            a = fmaf(hv.z, r2[m], a);
            a = fmaf(hv.w, r3[m], a);
            acc[m] = a;
        }
    }

    float o = 0.0f;
#pragma unroll
    for (int m = 0; m < JPW; ++m)
        o = fmaf(fmaxf(acc[m], 0.0f), W3p[jbase + m], o);

    red[t] = o;
    __syncthreads();

    float tot = b3[0];
#pragma unroll
    for (int i = 0; i < 8; ++i) tot += red[(t & 63) + 64 * i];
    return 1.0f / (1.0f + __expf(-tot));
}

// ---------------------------------------------------------------------------
// Kernel 2: edge MLP pass 0 -> atomic scatter-add of effects to receivers.
// ---------------------------------------------------------------------------
__global__ __launch_bounds__(512) void edge0_kernel(
    const float* __restrict__ obj,
    const int* __restrict__ snd_idx, const int* __restrict__ rcv_idx,
    const float* __restrict__ rel,
    const float* __restrict__ W1, const float* __restrict__ b1,
    const float* __restrict__ W2p, const float* __restrict__ b2p,
    const float* __restrict__ W3p, const float* __restrict__ b3,
    float* __restrict__ eff_rcv)
{
    __shared__ float h1s[64 * LSTR];
    __shared__ float red[512];

    const int t = (int)threadIdx.x;
    const int ebase = (int)blockIdx.x * 64;
    const int e = t & 63;
    const int jg = t >> 6;
    const int eg = ebase + e;
    const int b = eg >> 13;

    float x[7];
    {
        const int sn = snd_idx[eg];
        const int rn = rcv_idx[eg];
        const float* ps = obj + ((b << 11) + sn) * 3;
        const float* pr = obj + ((b << 11) + rn) * 3;
        x[0] = ps[0]; x[1] = ps[1]; x[2] = ps[2];
        x[3] = pr[0]; x[4] = pr[1]; x[5] = pr[2];
        x[6] = rel[eg];
    }

    const float eff = edge_mlp_body(x, t, e, jg, W1, b1, W2p, b2p, W3p, b3, h1s, red);
    if (t < 64) atomicAdd(&eff_rcv[(b << 11) + rcv_idx[eg]], eff);
}

// ---------------------------------------------------------------------------
// Kernel 3: fused object-MLP prologue + edge MLP pass 1 -> final edge weights.
// Threads 0..127 recompute obj_new for the <=128 nodes this block's edges
// touch (redundant across blocks, ~1us); edge body then reads x from LDS.
// ---------------------------------------------------------------------------
__global__ __launch_bounds__(512) void edge1_kernel(
    const float* __restrict__ objects, const float* __restrict__ eff_rcv,
    const int* __restrict__ snd_idx, const int* __restrict__ rcv_idx,
    const float* __restrict__ rel,
    const float* __restrict__ oW1, const float* __restrict__ ob1,
    const float* __restrict__ oW2, const float* __restrict__ ob2,
    const float* __restrict__ W1, const float* __restrict__ b1,
    const float* __restrict__ W2p, const float* __restrict__ b2p,
    const float* __restrict__ W3p, const float* __restrict__ b3,
    float* __restrict__ out)
{
    __shared__ float h1s[64 * LSTR];
    __shared__ float red[512];
    __shared__ int   nds[128];          // sender nodes [0..64), receiver [64..128)
    __shared__ float onew[128][3];

    const int t = (int)threadIdx.x;
    const int ebase = (int)blockIdx.x * 64;
    const int e = t & 63;
    const int jg = t >> 6;
    const int eg = ebase + e;
    const int b = ebase >> 13;          // uniform per block

    if (t < 64)       nds[t] = snd_idx[ebase + t];
    else if (t < 128) nds[t] = rcv_idx[ebase + (t - 64)];
    __syncthreads();

    // object MLP (4 -> 100 relu -> 3) for this block's nodes
    if (t < 128) {
        const int node = (b << 11) + nds[t];
        const float x0 = objects[node * 3 + 0];
        const float x1 = objects[node * 3 + 1];
        const float x2 = objects[node * 3 + 2];
        const float x3 = eff_rcv[node];
        float a0 = ob2[0], a1 = ob2[1], a2 = ob2[2];
#pragma unroll 4
        for (int j = 0; j < OH; ++j) {
            float h = ob1[j];
            h = fmaf(x0, oW1[0 * OH + j], h);
            h = fmaf(x1, oW1[1 * OH + j], h);
            h = fmaf(x2, oW1[2 * OH + j], h);
            h = fmaf(x3, oW1[3 * OH + j], h);
            h = fmaxf(h, 0.0f);
            a0 = fmaf(h, oW2[j * 3 + 0], a0);
            a1 = fmaf(h, oW2[j * 3 + 1], a1);
            a2 = fmaf(h, oW2[j * 3 + 2], a2);
        }
        onew[t][0] = a0; onew[t][1] = a1; onew[t][2] = a2;
    }
    __syncthreads();

    float x[7];
    x[0] = onew[e][0];      x[1] = onew[e][1];      x[2] = onew[e][2];
    x[3] = onew[64 + e][0]; x[4] = onew[64 + e][1]; x[5] = onew[64 + e][2];
    x[6] = rel[eg];

    const float eff = edge_mlp_body(x, t, e, jg, W1, b1, W2p, b2p, W3p, b3, h1s, red);
    if (t < 64) out[eg] = eff;
}

// ---------------------------------------------------------------------------
extern "C" void kernel_launch(void* const* d_in, const int* in_sizes, int n_in,
                              void* d_out, int out_size, void* d_ws, size_t ws_size,
                              hipStream_t stream) {
    (void)in_sizes; (void)n_in; (void)out_size; (void)ws_size;

    const float* objects = (const float*)d_in[0];
    const float* S       = (const float*)d_in[1];
    const float* R       = (const float*)d_in[2];
    const float* rel     = (const float*)d_in[3];
    const float* rW1     = (const float*)d_in[4];
    const float* rb1     = (const float*)d_in[5];
    const float* rW2     = (const float*)d_in[6];
    const float* rb2     = (const float*)d_in[7];
    const float* rW3     = (const float*)d_in[8];
    const float* rb3     = (const float*)d_in[9];
    const float* oW1     = (const float*)d_in[10];
    const float* ob1     = (const float*)d_in[11];
    const float* oW2     = (const float*)d_in[12];
    const float* ob2     = (const float*)d_in[13];

    char* ws = (char*)d_ws;
    int*   snd_idx = (int*)(ws + 0);               // 128 KiB
    int*   rcv_idx = (int*)(ws + (128 << 10));     // 128 KiB
    float* eff_rcv = (float*)(ws + (256 << 10));   //  32 KiB
    float* W2p     = (float*)(ws + (288 << 10));   //  ~92 KiB
    float* b2p     = (float*)(ws + (384 << 10));   //  608 B
    float* W3p     = (float*)(ws + (385 << 10));   //  608 B

    // 1) scan one-hot matrices + pad weights + zero eff_rcv  (HBM-bound)
    scan_prep_kernel<<<4096, 256, 0, stream>>>(
        S, R, rW2, rb2, rW3, snd_idx, rcv_idx, W2p, b2p, W3p, eff_rcv);

    // 2) edge MLP pass 0 -> scatter-add effects to receivers
    edge0_kernel<<<(BB * EE) / 64, 512, 0, stream>>>(
        objects, snd_idx, rcv_idx, rel, rW1, rb1, W2p, b2p, W3p, rb3, eff_rcv);

    // 3) fused object MLP + final relational pass -> edge weights
    edge1_kernel<<<(BB * EE) / 64, 512, 0, stream>>>(
        objects, eff_rcv, snd_idx, rcv_idx, rel, oW1, ob1, oW2, ob2,
        rW1, rb1, W2p, b2p, W3p, rb3, (float*)d_out);
}

// Round 6
// 113.939 us; speedup vs baseline: 7.4774x; 1.1945x over previous
//
#include <hip/hip_runtime.h>
#include <hip/hip_bf16.h>

#define BB 4
#define NN 2048
#define EE 8192
#define RH 150
#define NP 160        // padded hidden dim for MFMA (10 n-tiles / 5 k-steps of 32)
#define HSTR 168      // h1bf LDS row stride (ushorts): mult of 8 (16B align)
#define RSTR 36       // red2 LDS row stride (floats)
#define OH 100

typedef float f4_t   __attribute__((ext_vector_type(4)));
typedef short short8 __attribute__((ext_vector_type(8)));
typedef float f32x4  __attribute__((ext_vector_type(4)));

__device__ __forceinline__ unsigned short f2bf(float f) {
    __hip_bfloat16 h = __float2bfloat16(f);
    return *reinterpret_cast<unsigned short*>(&h);
}

// ---------------------------------------------------------------------------
// Kernel 1: scan both one-hot matrices -> indices; prep bf16-transposed W2
// (w2t[n][k], zero-padded 160x160), padded b2/W3, zero eff_rcv. One dispatch.
// blocks [0,2048) scan S, [2048,4096) scan R. Non-temporal float4 streaming.
// ---------------------------------------------------------------------------
__global__ __launch_bounds__(256) void scan_prep_kernel(
    const float* __restrict__ S, const float* __restrict__ R,
    const float* __restrict__ rW2, const float* __restrict__ rb2,
    const float* __restrict__ rW3,
    int* __restrict__ snd_idx, int* __restrict__ rcv_idx,
    unsigned short* __restrict__ w2t, float* __restrict__ b2p,
    float* __restrict__ w3p, float* __restrict__ eff_rcv)
{
    const unsigned gtid = blockIdx.x * 256u + threadIdx.x;

    // ---- prep: bf16-transpose W2 (w2t[n][k] = W2[k][n]), pad b2/W3, zero ----
    if (gtid < NP * NP) {
        const int n = (int)gtid / NP, k = (int)gtid - n * NP;
        w2t[gtid] = (n < RH && k < RH) ? f2bf(rW2[k * RH + n]) : (unsigned short)0;
    }
    if (gtid < NP) {
        b2p[gtid] = (gtid < RH) ? rb2[gtid] : 0.0f;
        w3p[gtid] = (gtid < RH) ? rW3[gtid] : 0.0f;
    }
    if (gtid < BB * NN) eff_rcv[gtid] = 0.0f;

    // ---- scan ----
    const bool second = blockIdx.x >= 2048;
    const float* __restrict__ M = second ? R : S;
    int* __restrict__ idx = second ? rcv_idx : snd_idx;

    const unsigned total4 = (unsigned)BB * NN * EE / 4u;  // 16,777,216
    unsigned i = (blockIdx.x & 2047u) * 256u + threadIdx.x;
    const unsigned stride = 2048u * 256u;
    for (; i < total4; i += stride) {
        const f4_t v = __builtin_nontemporal_load(reinterpret_cast<const f4_t*>(M) + i);
        if (v.x > 0.5f || v.y > 0.5f || v.z > 0.5f || v.w > 0.5f) {
            const unsigned flat = i * 4u;
            const unsigned e = flat & (EE - 1u);
            const unsigned n = (flat >> 13) & (NN - 1u);
            const unsigned b = flat >> 24;
            if (v.x > 0.5f) idx[b * EE + e + 0u] = (int)n;
            if (v.y > 0.5f) idx[b * EE + e + 1u] = (int)n;
            if (v.z > 0.5f) idx[b * EE + e + 2u] = (int)n;
            if (v.w > 0.5f) idx[b * EE + e + 3u] = (int)n;
        }
    }
}

// ---------------------------------------------------------------------------
// Edge-MLP body, MFMA version. 512 threads = 8 waves, 64 edges per block.
//  layer 1 (fp32 VALU): thread t -> edge e=t&63, neurons j = (t>>6)+8*i;
//          h1 written to LDS as bf16, row stride HSTR.
//  layer 2 (MFMA): H2[64x160] = H1[64x160] x W2[160x160] via 16x16x32 bf16.
//          wave w: group g=w>>2 (n-tiles g*5..g*5+4), m-tile m=w&3.
//          A-frag: lane l = row(l&15) + 16*kchunk(l>>4), 8 contiguous k.
//          B-frag: lane l = col(l&15) + 16*kchunk(l>>4), from w2t[n][k].
//          C-frag: col=l&15, row=(l>>4)*4+reg (m89-verified).
//  layer 3: relu(C)*W3 in epilogue, 2-group LDS reduction, sigmoid.
// Returns edge weight for t<64, else 0.
// ---------------------------------------------------------------------------
__device__ __forceinline__ float edge_mlp_body(
    const float x[7], int t,
    const float* __restrict__ W1, const float* __restrict__ b1,
    const unsigned short* __restrict__ w2t, const float* __restrict__ b2p,
    const float* __restrict__ w3p, const float* __restrict__ b3,
    unsigned short* __restrict__ h1bf, float* __restrict__ red2)
{
    const int e  = t & 63;
    const int w  = t >> 6;               // wave index, uniform

    // ---- layer 1 (fp32) -> h1bf in LDS ----
    for (int j = w; j < NP; j += 8) {
        float v = 0.0f;
        if (j < RH) {
            v = b1[j];
#pragma unroll
            for (int k = 0; k < 7; ++k) v = fmaf(x[k], W1[k * RH + j], v);
            v = fmaxf(v, 0.0f);
        }
        h1bf[e * HSTR + j] = f2bf(v);
    }
    __syncthreads();

    // ---- layer 2 (MFMA) ----
    const int lane = t & 63;
    const int g = w >> 2;                // n-tile group (0: tiles 0-4, 1: 5-9)
    const int m = w & 3;                 // m-tile (edges m*16 .. m*16+15)
    const int c  = lane & 15;
    const int kg = lane >> 4;

    f32x4 acc[5];
#pragma unroll
    for (int nti = 0; nti < 5; ++nti) {
        const float bi = b2p[(g * 5 + nti) * 16 + c];
        acc[nti] = (f32x4){bi, bi, bi, bi};
    }

#pragma unroll
    for (int ks = 0; ks < 5; ++ks) {
        const short8 a = *reinterpret_cast<const short8*>(
            &h1bf[(m * 16 + c) * HSTR + ks * 32 + kg * 8]);
#pragma unroll
        for (int nti = 0; nti < 5; ++nti) {
            const int n = (g * 5 + nti) * 16 + c;
            const short8 bfr = *reinterpret_cast<const short8*>(
                &w2t[n * NP + ks * 32 + kg * 8]);
            acc[nti] = __builtin_amdgcn_mfma_f32_16x16x32_bf16(a, bfr, acc[nti], 0, 0, 0);
        }
    }

    // ---- layer 3 epilogue: relu * W3, per-lane partials ----
    float p0 = 0.0f, p1 = 0.0f, p2 = 0.0f, p3 = 0.0f;
#pragma unroll
    for (int nti = 0; nti < 5; ++nti) {
        const int n = (g * 5 + nti) * 16 + c;
        const float w3v = w3p[n];
        p0 = fmaf(fmaxf(acc[nti][0], 0.0f), w3v, p0);
        p1 = fmaf(fmaxf(acc[nti][1], 0.0f), w3v, p1);
        p2 = fmaf(fmaxf(acc[nti][2], 0.0f), w3v, p2);
        p3 = fmaf(fmaxf(acc[nti][3], 0.0f), w3v, p3);
    }
    {
        const int er = m * 16 + kg * 4;  // C-frag row base for this lane
        red2[(er + 0) * RSTR + g * 16 + c] = p0;
        red2[(er + 1) * RSTR + g * 16 + c] = p1;
        red2[(er + 2) * RSTR + g * 16 + c] = p2;
        red2[(er + 3) * RSTR + g * 16 + c] = p3;
    }
    __syncthreads();

    if (t >= 64) return 0.0f;
    float tot = b3[0];
#pragma unroll
    for (int i = 0; i < 32; ++i) tot += red2[t * RSTR + i];
    return 1.0f / (1.0f + __expf(-tot));
}

// ---------------------------------------------------------------------------
// Kernel 2: edge MLP pass 0 -> atomic scatter-add of effects to receivers.
// ---------------------------------------------------------------------------
__global__ __launch_bounds__(512, 4) void edge0_kernel(
    const float* __restrict__ obj,
    const int* __restrict__ snd_idx, const int* __restrict__ rcv_idx,
    const float* __restrict__ rel,
    const float* __restrict__ W1, const float* __restrict__ b1,
    const unsigned short* __restrict__ w2t, const float* __restrict__ b2p,
    const float* __restrict__ w3p, const float* __restrict__ b3,
    float* __restrict__ eff_rcv)
{
    __shared__ unsigned short h1bf[64 * HSTR];
    __shared__ float red2[64 * RSTR];

    const int t = (int)threadIdx.x;
    const int ebase = (int)blockIdx.x * 64;
    const int eg = ebase + (t & 63);
    const int b = eg >> 13;

    float x[7];
    {
        const int sn = snd_idx[eg];
        const int rn = rcv_idx[eg];
        const float* ps = obj + ((b << 11) + sn) * 3;
        const float* pr = obj + ((b << 11) + rn) * 3;
        x[0] = ps[0]; x[1] = ps[1]; x[2] = ps[2];
        x[3] = pr[0]; x[4] = pr[1]; x[5] = pr[2];
        x[6] = rel[eg];
    }

    const float eff = edge_mlp_body(x, t, W1, b1, w2t, b2p, w3p, b3, h1bf, red2);
    if (t < 64) atomicAdd(&eff_rcv[(b << 11) + rcv_idx[eg]], eff);
}

// ---------------------------------------------------------------------------
// Kernel 3: fused object-MLP prologue + edge MLP pass 1 -> final edge weights.
// ---------------------------------------------------------------------------
__global__ __launch_bounds__(512, 4) void edge1_kernel(
    const float* __restrict__ objects, const float* __restrict__ eff_rcv,
    const int* __restrict__ snd_idx, const int* __restrict__ rcv_idx,
    const float* __restrict__ rel,
    const float* __restrict__ oW1, const float* __restrict__ ob1,
    const float* __restrict__ oW2, const float* __restrict__ ob2,
    const float* __restrict__ W1, const float* __restrict__ b1,
    const unsigned short* __restrict__ w2t, const float* __restrict__ b2p,
    const float* __restrict__ w3p, const float* __restrict__ b3,
    float* __restrict__ out)
{
    __shared__ unsigned short h1bf[64 * HSTR];
    __shared__ float red2[64 * RSTR];
    __shared__ int   nds[128];          // senders [0..64), receivers [64..128)
    __shared__ float onew[128][3];

    const int t = (int)threadIdx.x;
    const int ebase = (int)blockIdx.x * 64;
    const int e = t & 63;
    const int eg = ebase + e;
    const int b = ebase >> 13;          // uniform per block

    if (t < 64)       nds[t] = snd_idx[ebase + t];
    else if (t < 128) nds[t] = rcv_idx[ebase + (t - 64)];
    __syncthreads();

    // object MLP (4 -> 100 relu -> 3) for this block's touched nodes
    if (t < 128) {
        const int node = (b << 11) + nds[t];
        const float x0 = objects[node * 3 + 0];
        const float x1 = objects[node * 3 + 1];
        const float x2 = objects[node * 3 + 2];
        const float x3 = eff_rcv[node];
        float a0 = ob2[0], a1 = ob2[1], a2 = ob2[2];
#pragma unroll 4
        for (int j = 0; j < OH; ++j) {
            float h = ob1[j];
            h = fmaf(x0, oW1[0 * OH + j], h);
            h = fmaf(x1, oW1[1 * OH + j], h);
            h = fmaf(x2, oW1[2 * OH + j], h);
            h = fmaf(x3, oW1[3 * OH + j], h);
            h = fmaxf(h, 0.0f);
            a0 = fmaf(h, oW2[j * 3 + 0], a0);
            a1 = fmaf(h, oW2[j * 3 + 1], a1);
            a2 = fmaf(h, oW2[j * 3 + 2], a2);
        }
        onew[t][0] = a0; onew[t][1] = a1; onew[t][2] = a2;
    }
    __syncthreads();

    float x[7];
    x[0] = onew[e][0];      x[1] = onew[e][1];      x[2] = onew[e][2];
    x[3] = onew[64 + e][0]; x[4] = onew[64 + e][1]; x[5] = onew[64 + e][2];
    x[6] = rel[eg];

    const float eff = edge_mlp_body(x, t, W1, b1, w2t, b2p, w3p, b3, h1bf, red2);
    if (t < 64) out[eg] = eff;
}

// ---------------------------------------------------------------------------
extern "C" void kernel_launch(void* const* d_in, const int* in_sizes, int n_in,
                              void* d_out, int out_size, void* d_ws, size_t ws_size,
                              hipStream_t stream) {
    (void)in_sizes; (void)n_in; (void)out_size; (void)ws_size;

    const float* objects = (const float*)d_in[0];
    const float* S       = (const float*)d_in[1];
    const float* R       = (const float*)d_in[2];
    const float* rel     = (const float*)d_in[3];
    const float* rW1     = (const float*)d_in[4];
    const float* rb1     = (const float*)d_in[5];
    const float* rW2     = (const float*)d_in[6];
    const float* rb2     = (const float*)d_in[7];
    const float* rW3     = (const float*)d_in[8];
    const float* rb3     = (const float*)d_in[9];
    const float* oW1     = (const float*)d_in[10];
    const float* ob1     = (const float*)d_in[11];
    const float* oW2     = (const float*)d_in[12];
    const float* ob2     = (const float*)d_in[13];

    char* ws = (char*)d_ws;
    int*            snd_idx = (int*)(ws + 0);               // 128 KiB
    int*            rcv_idx = (int*)(ws + (128 << 10));     // 128 KiB
    float*          eff_rcv = (float*)(ws + (256 << 10));   //  32 KiB
    unsigned short* w2t     = (unsigned short*)(ws + (288 << 10)); // 50 KiB
    float*          b2p     = (float*)(ws + (344 << 10));   //  640 B
    float*          w3p     = (float*)(ws + (345 << 10));   //  640 B

    // 1) scan one-hot matrices + prep bf16 weights + zero eff_rcv (HBM-bound)
    scan_prep_kernel<<<4096, 256, 0, stream>>>(
        S, R, rW2, rb2, rW3, snd_idx, rcv_idx, w2t, b2p, w3p, eff_rcv);

    // 2) edge MLP pass 0 (MFMA layer 2) -> scatter-add effects
    edge0_kernel<<<(BB * EE) / 64, 512, 0, stream>>>(
        objects, snd_idx, rcv_idx, rel, rW1, rb1, w2t, b2p, w3p, rb3, eff_rcv);

    // 3) fused object MLP + final relational pass (MFMA) -> edge weights
    edge1_kernel<<<(BB * EE) / 64, 512, 0, stream>>>(
        objects, eff_rcv, snd_idx, rcv_idx, rel, oW1, ob1, oW2, ob2,
        rW1, rb1, w2t, b2p, w3p, rb3, (float*)d_out);
}